// Round 13
// baseline (277.363 us; speedup 1.0000x reference)
//
#include <hip/hip_runtime.h>

// LightGCN: 3-layer propagation, 1.6M edges, D=128.
// R13: EPW 4096 -> 2048. Gathers are CLOSED at the hardware ceiling: three
// different instruction mixes (R10/R11/R12) all plateau at ~3.7 TB/s with
// FETCH at the compulsory 8-XCD-replication floor (231/187 MB). Remaining
// lever is the build: 391 partition blocks = 1.53/CU made the partition
// critical path one block's full serial duration; 782 blocks (3.05/CU,
// ~20KB LDS) halve per-block work while fixed cost (391-bucket scan) stays
// minor. Gather/fill2/meta = R12 proven.

static constexpr int USERS  = 50000;
static constexpr int NNODES = 100000;
static constexpr int DIM    = 128;
static constexpr int NEDGES = 1600000;
static constexpr long NELEM = (long)NNODES * DIM;     // 12.8M
static constexpr int NBK    = (NNODES + 255) / 256;   // 391 buckets x 256 nodes
static constexpr int EPW    = 2048;                   // edges per partition WG
static constexpr int NWG    = (NEDGES + EPW - 1) / EPW; // 782
static constexpr int SSROW  = NBK + 1;                // 392
static constexpr int INITB  = (int)((NELEM / 16 + 255) / 256); // 3125
static constexpr int SCAP   = 5120;                   // fill2 LDS stage capacity

__device__ __forceinline__ unsigned short f2bf(float f) {
    unsigned int u = __float_as_uint(f);
    unsigned int r = (u + 0x7FFFu + ((u >> 16) & 1)) >> 16;
    return (unsigned short)r;
}
__device__ __forceinline__ unsigned int pack2(float a, float b) {
    return (unsigned int)f2bf(a) | ((unsigned int)f2bf(b) << 16);
}
__device__ __forceinline__ float bflo(unsigned int p) { return __uint_as_float(p << 16); }
__device__ __forceinline__ float bfhi(unsigned int p) { return __uint_as_float(p & 0xFFFF0000u); }

// ---------- fused: blocks [0,NWG) partition edges; rest convert embeds ----------
__global__ void __launch_bounds__(256) initpart_k(
    const float* __restrict__ uE, const float* __restrict__ iE,
    const int* __restrict__ esrc, const int* __restrict__ edst,
    const float* __restrict__ eval,
    unsigned int* __restrict__ E0, int* __restrict__ ssP,
    int* __restrict__ gcnt, int2* __restrict__ tmp) {
    __shared__ int2 stage[EPW];            // 16 KB
    __shared__ int hist[NBK];
    __shared__ int cursor[NBK];
    __shared__ int sp[256];
    int t = threadIdx.x;

    if (blockIdx.x >= NWG) {
        long base = ((long)(blockIdx.x - NWG) * 256 + t) * 16;
        if (base >= NELEM) return;
        const long usplit = (long)USERS * DIM;     // 6.4M, divisible by 16
        const float* s = (base < usplit) ? (uE + base) : (iE + (base - usplit));
        #pragma unroll
        for (int h = 0; h < 2; ++h) {
            float4 f0 = *(const float4*)(s + h * 8);
            float4 f1 = *(const float4*)(s + h * 8 + 4);
            uint4 o;
            o.x = pack2(f0.x, f0.y); o.y = pack2(f0.z, f0.w);
            o.z = pack2(f1.x, f1.y); o.w = pack2(f1.z, f1.w);
            *(uint4*)(E0 + base / 2 + h * 4) = o;
        }
        return;
    }

    int w = blockIdx.x;
    int ebase = w * EPW;
    int n = NEDGES - ebase; if (n > EPW) n = EPW;

    for (int b = t; b < NBK; b += 256) hist[b] = 0;
    __syncthreads();
    #pragma unroll
    for (int k = 0; k < EPW / 256; ++k) {
        int idx = k * 256 + t;
        if (idx < n) atomicAdd(&hist[edst[ebase + idx] >> 8], 1);
    }
    __syncthreads();
    for (int b = t; b < NBK; b += 256)
        if (hist[b]) atomicAdd(&gcnt[b], hist[b]);
    int b0 = 2 * t, b1 = 2 * t + 1;
    int v0 = (b0 < NBK) ? hist[b0] : 0;
    int v1 = (b1 < NBK) ? hist[b1] : 0;
    int psum = v0 + v1;
    sp[t] = psum;
    __syncthreads();
    for (int o = 1; o < 256; o <<= 1) {
        int x = (t >= o) ? sp[t - o] : 0;
        __syncthreads();
        sp[t] += x;
        __syncthreads();
    }
    int pref = sp[t] - psum;
    if (b0 < NBK) cursor[b0] = pref;
    if (b1 < NBK) cursor[b1] = pref + v0;
    __syncthreads();
    for (int b = t; b < NBK; b += 256) ssP[w * SSROW + b] = cursor[b];
    if (t == 0) ssP[w * SSROW + NBK] = n;
    __syncthreads();
    #pragma unroll
    for (int k = 0; k < EPW / 256; ++k) {
        int idx = k * 256 + t;
        if (idx < n) {
            int e = ebase + idx;
            int d = edst[e];
            int p = atomicAdd(&cursor[d >> 8], 1);
            stage[p] = make_int2(esrc[e] | ((d & 255) << 17), __float_as_int(eval[e]));
        }
    }
    __syncthreads();
    #pragma unroll
    for (int k = 0; k < EPW / 256; ++k) {
        int idx = k * 256 + t;
        if (idx < n) tmp[ebase + idx] = stage[idx];
    }
}

// per-bucket finalize, single-pass: LDS-stage bucket edges (no-atomic copy via
// per-thread length scan), count+scan -> rs[], place -> packed 4B meta.
__global__ void __launch_bounds__(256) fill2_k(
    const int2* __restrict__ tmp, const int* __restrict__ ssP,
    const int* __restrict__ gcnt,
    int* __restrict__ rs, unsigned int* __restrict__ meta) {
    __shared__ int2 stage[SCAP];           // 40 KB
    __shared__ int cnt[256];
    __shared__ int cur[256];
    __shared__ int sp2[256];
    __shared__ int sbase;
    int b = blockIdx.x, t = threadIdx.x;

    int b0 = 2 * t, b1 = 2 * t + 1;
    int g0 = (b0 < NBK) ? gcnt[b0] : 0;
    int g1 = (b1 < NBK) ? gcnt[b1] : 0;
    int ps = g0 + g1;
    sp2[t] = ps;
    __syncthreads();
    for (int o = 1; o < 256; o <<= 1) {
        int x = (t >= o) ? sp2[t - o] : 0;
        __syncthreads();
        sp2[t] += x;
        __syncthreads();
    }
    int pref = sp2[t] - ps;
    if (b0 == b) sbase = pref;
    if (b1 == b) sbase = pref + g0;
    if (b == 0 && t == 0) rs[NNODES] = NEDGES;
    __syncthreads();
    int base = sbase;

    int mylen = 0;
    for (int w = t; w < NWG; w += 256)
        mylen += ssP[w * SSROW + b + 1] - ssP[w * SSROW + b];
    sp2[t] = mylen;
    __syncthreads();
    for (int o = 1; o < 256; o <<= 1) {
        int x = (t >= o) ? sp2[t - o] : 0;
        __syncthreads();
        sp2[t] += x;
        __syncthreads();
    }
    int myoff = sp2[t] - mylen;
    int nb = sp2[255];
    __syncthreads();

    if (nb <= SCAP) {
        int o = myoff;
        for (int w = t; w < NWG; w += 256) {
            int s = ssP[w * SSROW + b];
            int e = ssP[w * SSROW + b + 1];
            const int2* seg = tmp + (long)w * EPW;
            for (int i = s; i < e; ++i) stage[o++] = seg[i];
        }
        cnt[t] = 0;
        __syncthreads();
        for (int i = t; i < nb; i += 256)
            atomicAdd(&cnt[(stage[i].x >> 17) & 255], 1);
        __syncthreads();
        int myc = cnt[t];
        sp2[t] = myc;
        __syncthreads();
        for (int o2 = 1; o2 < 256; o2 <<= 1) {
            int x = (t >= o2) ? sp2[t - o2] : 0;
            __syncthreads();
            sp2[t] += x;
            __syncthreads();
        }
        int start = base + sp2[t] - myc;
        int node = b * 256 + t;
        if (node < NNODES) rs[node] = start;
        cur[t] = start;
        __syncthreads();
        for (int i = t; i < nb; i += 256) {
            int2 m = stage[i];
            int slot = atomicAdd(&cur[(m.x >> 17) & 255], 1);
            unsigned int bv = (unsigned int)(f2bf(__int_as_float(m.y)) & 0x7FFF);
            meta[slot] = (unsigned int)(m.x & 0x1FFFF) | (bv << 17);
        }
    } else {
        cnt[t] = 0;
        __syncthreads();
        for (int w = t; w < NWG; w += 256) {
            int s = ssP[w * SSROW + b];
            int e = ssP[w * SSROW + b + 1];
            const int2* seg = tmp + (long)w * EPW;
            for (int i = s; i < e; ++i)
                atomicAdd(&cnt[(seg[i].x >> 17) & 255], 1);
        }
        __syncthreads();
        int myc = cnt[t];
        sp2[t] = myc;
        __syncthreads();
        for (int o2 = 1; o2 < 256; o2 <<= 1) {
            int x = (t >= o2) ? sp2[t - o2] : 0;
            __syncthreads();
            sp2[t] += x;
            __syncthreads();
        }
        int start = base + sp2[t] - myc;
        int node = b * 256 + t;
        if (node < NNODES) rs[node] = start;
        cur[t] = start;
        __syncthreads();
        for (int w = t; w < NWG; w += 256) {
            int s = ssP[w * SSROW + b];
            int e = ssP[w * SSROW + b + 1];
            const int2* seg = tmp + (long)w * EPW;
            for (int i = s; i < e; ++i) {
                int2 m = seg[i];
                int slot = atomicAdd(&cur[(m.x >> 17) & 255], 1);
                unsigned int bv = (unsigned int)(f2bf(__int_as_float(m.y)) & 0x7FFF);
                meta[slot] = (unsigned int)(m.x & 0x1FFFF) | (bv << 17);
            }
        }
    }
}

// ---------- gather core: uint4/lane, 16 lanes/row, 4-wide unroll, 2 banks ----------
__device__ __forceinline__ void gather_row_u4(
    const unsigned int* __restrict__ meta, const uint4* __restrict__ curU4,
    int beg, int end, int sub, float* __restrict__ s) {
    float a0[8], a1[8];
    #pragma unroll
    for (int j = 0; j < 8; ++j) { a0[j] = 0.f; a1[j] = 0.f; }
    int i = beg;
    for (; i + 4 <= end; i += 4) {
        unsigned int m0 = __builtin_nontemporal_load(&meta[i]);
        unsigned int m1 = __builtin_nontemporal_load(&meta[i + 1]);
        unsigned int m2 = __builtin_nontemporal_load(&meta[i + 2]);
        unsigned int m3 = __builtin_nontemporal_load(&meta[i + 3]);
        uint4 p0 = curU4[((m0 & 0x1FFFF) << 4) + sub];
        uint4 p1 = curU4[((m1 & 0x1FFFF) << 4) + sub];
        uint4 p2 = curU4[((m2 & 0x1FFFF) << 4) + sub];
        uint4 p3 = curU4[((m3 & 0x1FFFF) << 4) + sub];
        float v0 = __uint_as_float((m0 >> 17) << 16);
        float v1 = __uint_as_float((m1 >> 17) << 16);
        float v2 = __uint_as_float((m2 >> 17) << 16);
        float v3 = __uint_as_float((m3 >> 17) << 16);
        a0[0] += bflo(p0.x) * v0; a0[1] += bfhi(p0.x) * v0;
        a0[2] += bflo(p0.y) * v0; a0[3] += bfhi(p0.y) * v0;
        a0[4] += bflo(p0.z) * v0; a0[5] += bfhi(p0.z) * v0;
        a0[6] += bflo(p0.w) * v0; a0[7] += bfhi(p0.w) * v0;
        a1[0] += bflo(p1.x) * v1; a1[1] += bfhi(p1.x) * v1;
        a1[2] += bflo(p1.y) * v1; a1[3] += bfhi(p1.y) * v1;
        a1[4] += bflo(p1.z) * v1; a1[5] += bfhi(p1.z) * v1;
        a1[6] += bflo(p1.w) * v1; a1[7] += bfhi(p1.w) * v1;
        a0[0] += bflo(p2.x) * v2; a0[1] += bfhi(p2.x) * v2;
        a0[2] += bflo(p2.y) * v2; a0[3] += bfhi(p2.y) * v2;
        a0[4] += bflo(p2.z) * v2; a0[5] += bfhi(p2.z) * v2;
        a0[6] += bflo(p2.w) * v2; a0[7] += bfhi(p2.w) * v2;
        a1[0] += bflo(p3.x) * v3; a1[1] += bfhi(p3.x) * v3;
        a1[2] += bflo(p3.y) * v3; a1[3] += bfhi(p3.y) * v3;
        a1[4] += bflo(p3.z) * v3; a1[5] += bfhi(p3.z) * v3;
        a1[6] += bflo(p3.w) * v3; a1[7] += bfhi(p3.w) * v3;
    }
    for (; i < end; ++i) {
        unsigned int m = __builtin_nontemporal_load(&meta[i]);
        uint4 p = curU4[((m & 0x1FFFF) << 4) + sub];
        float v = __uint_as_float((m >> 17) << 16);
        a0[0] += bflo(p.x) * v; a0[1] += bfhi(p.x) * v;
        a0[2] += bflo(p.y) * v; a0[3] += bfhi(p.y) * v;
        a0[4] += bflo(p.z) * v; a0[5] += bfhi(p.z) * v;
        a0[6] += bflo(p.w) * v; a0[7] += bfhi(p.w) * v;
    }
    #pragma unroll
    for (int j = 0; j < 8; ++j) s[j] = a0[j] + a1[j];
}

// ---------- gather (layers 1,2): 4 rows/wave, 16 rows/block ----------
__global__ void __launch_bounds__(256) gather_k(
    const int* __restrict__ rs, const unsigned int* __restrict__ meta,
    const uint4* __restrict__ cur, uint4* __restrict__ nxt) {
    int lane = threadIdx.x & 63;
    int row = blockIdx.x * 16 + (threadIdx.x >> 6) * 4 + (lane >> 4);
    if (row >= NNODES) return;
    int sub = lane & 15;
    float s[8];
    gather_row_u4(meta, cur, rs[row], rs[row + 1], sub, s);
    nxt[(row << 4) + sub] = make_uint4(pack2(s[0], s[1]), pack2(s[2], s[3]),
                                       pack2(s[4], s[5]), pack2(s[6], s[7]));
}

// ---------- layer 3 fused with final: out = E0 + L1 + L2 + sum ----------
__global__ void __launch_bounds__(256) gather_last_k(
    const int* __restrict__ rs, const unsigned int* __restrict__ meta,
    const uint4* __restrict__ cur,   // = L2 buffer
    const uint4* __restrict__ L1,
    const uint4* __restrict__ E0,
    float* __restrict__ out) {
    int lane = threadIdx.x & 63;
    int row = blockIdx.x * 16 + (threadIdx.x >> 6) * 4 + (lane >> 4);
    if (row >= NNODES) return;
    int sub = lane & 15;
    float s[8];
    gather_row_u4(meta, cur, rs[row], rs[row + 1], sub, s);
    uint4 e0 = E0[(row << 4) + sub];
    uint4 l1 = L1[(row << 4) + sub];
    uint4 l2 = cur[(row << 4) + sub];
    float4 o0, o1;
    o0.x = bflo(e0.x) + bflo(l1.x) + bflo(l2.x) + s[0];
    o0.y = bfhi(e0.x) + bfhi(l1.x) + bfhi(l2.x) + s[1];
    o0.z = bflo(e0.y) + bflo(l1.y) + bflo(l2.y) + s[2];
    o0.w = bfhi(e0.y) + bfhi(l1.y) + bfhi(l2.y) + s[3];
    o1.x = bflo(e0.z) + bflo(l1.z) + bflo(l2.z) + s[4];
    o1.y = bfhi(e0.z) + bfhi(l1.z) + bfhi(l2.z) + s[5];
    o1.z = bflo(e0.w) + bflo(l1.w) + bflo(l2.w) + s[6];
    o1.w = bfhi(e0.w) + bfhi(l1.w) + bfhi(l2.w) + s[7];
    float* op = out + (long)row * DIM + sub * 8;
    *(float4*)(op)     = o0;
    *(float4*)(op + 4) = o1;
}

// ---------- fallback: R2 atomic path ----------
__global__ void init_f32_k(const float* __restrict__ uE, const float* __restrict__ iE,
                           float* __restrict__ acc, float* __restrict__ cur) {
    long base = ((long)blockIdx.x * blockDim.x + threadIdx.x) * 8;
    if (base >= NELEM) return;
    const long usplit = (long)USERS * DIM;
    const float* s = (base < usplit) ? (uE + base) : (iE + (base - usplit));
    float4 f0 = *(const float4*)(s);
    float4 f1 = *(const float4*)(s + 4);
    *(float4*)(acc + base)     = f0;
    *(float4*)(acc + base + 4) = f1;
    *(float4*)(cur + base)     = f0;
    *(float4*)(cur + base + 4) = f1;
}
__global__ void scatter_k(const int* __restrict__ esrc, const int* __restrict__ edst,
                          const float* __restrict__ eval,
                          const float* __restrict__ cur, float* __restrict__ nxt) {
    long g = (long)blockIdx.x * blockDim.x + threadIdx.x;
    if (g >= (long)NEDGES * 32) return;
    int e  = (int)(g >> 5);
    int d0 = ((int)g & 31) * 4;
    float v = eval[e];
    float4 x = *(const float4*)(cur + (long)esrc[e] * DIM + d0);
    float* o = nxt + (long)edst[e] * DIM + d0;
    unsafeAtomicAdd(o + 0, x.x * v);
    unsafeAtomicAdd(o + 1, x.y * v);
    unsafeAtomicAdd(o + 2, x.z * v);
    unsafeAtomicAdd(o + 3, x.w * v);
}
__global__ void add_k(float* __restrict__ acc, const float* __restrict__ nxt) {
    long g = ((long)blockIdx.x * blockDim.x + threadIdx.x) * 4;
    if (g >= NELEM) return;
    float4 a = *(const float4*)(acc + g);
    float4 n = *(const float4*)(nxt + g);
    a.x += n.x; a.y += n.y; a.z += n.z; a.w += n.w;
    *(float4*)(acc + g) = a;
}

extern "C" void kernel_launch(void* const* d_in, const int* in_sizes, int n_in,
                              void* d_out, int out_size, void* d_ws, size_t ws_size,
                              hipStream_t stream) {
    const float* uE   = (const float*)d_in[0];
    const float* iE   = (const float*)d_in[1];
    const int*   esrc = (const int*)d_in[2];
    const int*   edst = (const int*)d_in[3];
    const float* eval = (const float*)d_in[4];
    float* out = (float*)d_out;

    char* ws = (char*)d_ws;
    const long NU = NELEM / 2;                      // uints per layer buffer
    unsigned int* E0  = (unsigned int*)ws;          // 25.6 MB
    unsigned int* L1  = E0 + NU;                    // 25.6 MB
    unsigned int* L2b = L1 + NU;                    // 25.6 MB
    unsigned int* meta = (unsigned int*)(L2b + NU); // 6.4 MB (packed)
    int*  rs     = (int*)(meta + NEDGES);           // NNODES+1
    int*  gcnt   = rs + NNODES + 1;                 // NBK
    int*  ssP    = gcnt + NBK;                      // NWG*SSROW (1.23 MB)
    size_t need  = (size_t)((char*)(ssP + NWG * SSROW) - ws);
    int2* tmp = (int2*)L2b;

    if (ws_size >= need) {
        hipMemsetAsync(gcnt, 0, (size_t)NBK * sizeof(int), stream);
        initpart_k<<<NWG + INITB, 256, 0, stream>>>(uE, iE, esrc, edst, eval,
                                                    E0, ssP, gcnt, tmp);
        fill2_k<<<NBK, 256, 0, stream>>>(tmp, ssP, gcnt, rs, meta);

        const int gblocks = (NNODES + 15) / 16;
        gather_k<<<gblocks, 256, 0, stream>>>(rs, meta, (const uint4*)E0, (uint4*)L1);
        gather_k<<<gblocks, 256, 0, stream>>>(rs, meta, (const uint4*)L1, (uint4*)L2b);
        gather_last_k<<<gblocks, 256, 0, stream>>>(rs, meta, (const uint4*)L2b,
                                                   (const uint4*)L1, (const uint4*)E0, out);
    } else {
        float* bufA = (float*)ws;
        float* bufB = bufA + NELEM;
        const size_t SZ = (size_t)NELEM * sizeof(float);
        init_f32_k<<<(int)((NELEM / 8 + 255) / 256), 256, 0, stream>>>(uE, iE, out, bufA);
        float* cur = bufA;
        float* nxt = bufB;
        for (int l = 0; l < 3; ++l) {
            hipMemsetAsync(nxt, 0, SZ, stream);
            long nthreads = (long)NEDGES * 32;
            scatter_k<<<(int)((nthreads + 255) / 256), 256, 0, stream>>>(esrc, edst, eval, cur, nxt);
            add_k<<<(int)((NELEM / 4 + 255) / 256), 256, 0, stream>>>(out, nxt);
            float* t = cur; cur = nxt; nxt = t;
        }
    }
}

// Round 14
// 267.729 us; speedup vs baseline: 1.0360x; 1.0360x over previous
//
#include <hip/hip_runtime.h>

// LightGCN: 3-layer propagation, 1.6M edges, D=128.
// R14 = R12 revert (EPW 4096). R13 (EPW 2048) regressed: fixed per-block cost
// (391-bucket zero/scan/ssP export) x 2x blocks + 2x fill2 segment-descriptor
// traffic outweighed the halved critical path. EPW 4096 is the measured
// optimum (8192 and 2048 both worse). Gathers are at the hardware ceiling:
// R10/R11/R12's three instruction mixes all plateau at ~3.7 TB/s with FETCH
// at the compulsory 8-XCD-replication floor (231/187 MB).

static constexpr int USERS  = 50000;
static constexpr int NNODES = 100000;
static constexpr int DIM    = 128;
static constexpr int NEDGES = 1600000;
static constexpr long NELEM = (long)NNODES * DIM;     // 12.8M
static constexpr int NBK    = (NNODES + 255) / 256;   // 391 buckets x 256 nodes
static constexpr int EPW    = 4096;                   // edges per partition WG
static constexpr int NWG    = (NEDGES + EPW - 1) / EPW; // 391
static constexpr int SSROW  = NBK + 1;                // 392
static constexpr int INITB  = (int)((NELEM / 16 + 255) / 256); // 3125
static constexpr int SCAP   = 5120;                   // fill2 LDS stage capacity

__device__ __forceinline__ unsigned short f2bf(float f) {
    unsigned int u = __float_as_uint(f);
    unsigned int r = (u + 0x7FFFu + ((u >> 16) & 1)) >> 16;
    return (unsigned short)r;
}
__device__ __forceinline__ unsigned int pack2(float a, float b) {
    return (unsigned int)f2bf(a) | ((unsigned int)f2bf(b) << 16);
}
__device__ __forceinline__ float bflo(unsigned int p) { return __uint_as_float(p << 16); }
__device__ __forceinline__ float bfhi(unsigned int p) { return __uint_as_float(p & 0xFFFF0000u); }

// ---------- fused: blocks [0,NWG) partition edges; rest convert embeds ----------
__global__ void __launch_bounds__(256) initpart_k(
    const float* __restrict__ uE, const float* __restrict__ iE,
    const int* __restrict__ esrc, const int* __restrict__ edst,
    const float* __restrict__ eval,
    unsigned int* __restrict__ E0, int* __restrict__ ssP,
    int* __restrict__ gcnt, int2* __restrict__ tmp) {
    __shared__ int2 stage[EPW];            // 32 KB
    __shared__ int hist[NBK];
    __shared__ int cursor[NBK];
    __shared__ int sp[256];
    int t = threadIdx.x;

    if (blockIdx.x >= NWG) {
        long base = ((long)(blockIdx.x - NWG) * 256 + t) * 16;
        if (base >= NELEM) return;
        const long usplit = (long)USERS * DIM;     // 6.4M, divisible by 16
        const float* s = (base < usplit) ? (uE + base) : (iE + (base - usplit));
        #pragma unroll
        for (int h = 0; h < 2; ++h) {
            float4 f0 = *(const float4*)(s + h * 8);
            float4 f1 = *(const float4*)(s + h * 8 + 4);
            uint4 o;
            o.x = pack2(f0.x, f0.y); o.y = pack2(f0.z, f0.w);
            o.z = pack2(f1.x, f1.y); o.w = pack2(f1.z, f1.w);
            *(uint4*)(E0 + base / 2 + h * 4) = o;
        }
        return;
    }

    int w = blockIdx.x;
    int ebase = w * EPW;
    int n = NEDGES - ebase; if (n > EPW) n = EPW;

    for (int b = t; b < NBK; b += 256) hist[b] = 0;
    __syncthreads();
    #pragma unroll
    for (int k = 0; k < EPW / 256; ++k) {
        int idx = k * 256 + t;
        if (idx < n) atomicAdd(&hist[edst[ebase + idx] >> 8], 1);
    }
    __syncthreads();
    for (int b = t; b < NBK; b += 256)
        if (hist[b]) atomicAdd(&gcnt[b], hist[b]);
    int b0 = 2 * t, b1 = 2 * t + 1;
    int v0 = (b0 < NBK) ? hist[b0] : 0;
    int v1 = (b1 < NBK) ? hist[b1] : 0;
    int psum = v0 + v1;
    sp[t] = psum;
    __syncthreads();
    for (int o = 1; o < 256; o <<= 1) {
        int x = (t >= o) ? sp[t - o] : 0;
        __syncthreads();
        sp[t] += x;
        __syncthreads();
    }
    int pref = sp[t] - psum;
    if (b0 < NBK) cursor[b0] = pref;
    if (b1 < NBK) cursor[b1] = pref + v0;
    __syncthreads();
    for (int b = t; b < NBK; b += 256) ssP[w * SSROW + b] = cursor[b];
    if (t == 0) ssP[w * SSROW + NBK] = n;
    __syncthreads();
    #pragma unroll
    for (int k = 0; k < EPW / 256; ++k) {
        int idx = k * 256 + t;
        if (idx < n) {
            int e = ebase + idx;
            int d = edst[e];
            int p = atomicAdd(&cursor[d >> 8], 1);
            stage[p] = make_int2(esrc[e] | ((d & 255) << 17), __float_as_int(eval[e]));
        }
    }
    __syncthreads();
    #pragma unroll
    for (int k = 0; k < EPW / 256; ++k) {
        int idx = k * 256 + t;
        if (idx < n) tmp[ebase + idx] = stage[idx];
    }
}

// per-bucket finalize, single-pass: LDS-stage bucket edges (no-atomic copy via
// per-thread length scan), count+scan -> rs[], place -> packed 4B meta.
__global__ void __launch_bounds__(256) fill2_k(
    const int2* __restrict__ tmp, const int* __restrict__ ssP,
    const int* __restrict__ gcnt,
    int* __restrict__ rs, unsigned int* __restrict__ meta) {
    __shared__ int2 stage[SCAP];           // 40 KB
    __shared__ int cnt[256];
    __shared__ int cur[256];
    __shared__ int sp2[256];
    __shared__ int sbase;
    int b = blockIdx.x, t = threadIdx.x;

    int b0 = 2 * t, b1 = 2 * t + 1;
    int g0 = (b0 < NBK) ? gcnt[b0] : 0;
    int g1 = (b1 < NBK) ? gcnt[b1] : 0;
    int ps = g0 + g1;
    sp2[t] = ps;
    __syncthreads();
    for (int o = 1; o < 256; o <<= 1) {
        int x = (t >= o) ? sp2[t - o] : 0;
        __syncthreads();
        sp2[t] += x;
        __syncthreads();
    }
    int pref = sp2[t] - ps;
    if (b0 == b) sbase = pref;
    if (b1 == b) sbase = pref + g0;
    if (b == 0 && t == 0) rs[NNODES] = NEDGES;
    __syncthreads();
    int base = sbase;

    int mylen = 0;
    for (int w = t; w < NWG; w += 256)
        mylen += ssP[w * SSROW + b + 1] - ssP[w * SSROW + b];
    sp2[t] = mylen;
    __syncthreads();
    for (int o = 1; o < 256; o <<= 1) {
        int x = (t >= o) ? sp2[t - o] : 0;
        __syncthreads();
        sp2[t] += x;
        __syncthreads();
    }
    int myoff = sp2[t] - mylen;
    int nb = sp2[255];
    __syncthreads();

    if (nb <= SCAP) {
        int o = myoff;
        for (int w = t; w < NWG; w += 256) {
            int s = ssP[w * SSROW + b];
            int e = ssP[w * SSROW + b + 1];
            const int2* seg = tmp + (long)w * EPW;
            for (int i = s; i < e; ++i) stage[o++] = seg[i];
        }
        cnt[t] = 0;
        __syncthreads();
        for (int i = t; i < nb; i += 256)
            atomicAdd(&cnt[(stage[i].x >> 17) & 255], 1);
        __syncthreads();
        int myc = cnt[t];
        sp2[t] = myc;
        __syncthreads();
        for (int o2 = 1; o2 < 256; o2 <<= 1) {
            int x = (t >= o2) ? sp2[t - o2] : 0;
            __syncthreads();
            sp2[t] += x;
            __syncthreads();
        }
        int start = base + sp2[t] - myc;
        int node = b * 256 + t;
        if (node < NNODES) rs[node] = start;
        cur[t] = start;
        __syncthreads();
        for (int i = t; i < nb; i += 256) {
            int2 m = stage[i];
            int slot = atomicAdd(&cur[(m.x >> 17) & 255], 1);
            unsigned int bv = (unsigned int)(f2bf(__int_as_float(m.y)) & 0x7FFF);
            meta[slot] = (unsigned int)(m.x & 0x1FFFF) | (bv << 17);
        }
    } else {
        cnt[t] = 0;
        __syncthreads();
        for (int w = t; w < NWG; w += 256) {
            int s = ssP[w * SSROW + b];
            int e = ssP[w * SSROW + b + 1];
            const int2* seg = tmp + (long)w * EPW;
            for (int i = s; i < e; ++i)
                atomicAdd(&cnt[(seg[i].x >> 17) & 255], 1);
        }
        __syncthreads();
        int myc = cnt[t];
        sp2[t] = myc;
        __syncthreads();
        for (int o2 = 1; o2 < 256; o2 <<= 1) {
            int x = (t >= o2) ? sp2[t - o2] : 0;
            __syncthreads();
            sp2[t] += x;
            __syncthreads();
        }
        int start = base + sp2[t] - myc;
        int node = b * 256 + t;
        if (node < NNODES) rs[node] = start;
        cur[t] = start;
        __syncthreads();
        for (int w = t; w < NWG; w += 256) {
            int s = ssP[w * SSROW + b];
            int e = ssP[w * SSROW + b + 1];
            const int2* seg = tmp + (long)w * EPW;
            for (int i = s; i < e; ++i) {
                int2 m = seg[i];
                int slot = atomicAdd(&cur[(m.x >> 17) & 255], 1);
                unsigned int bv = (unsigned int)(f2bf(__int_as_float(m.y)) & 0x7FFF);
                meta[slot] = (unsigned int)(m.x & 0x1FFFF) | (bv << 17);
            }
        }
    }
}

// ---------- gather core: uint4/lane, 16 lanes/row, 4-wide unroll, 2 banks ----------
__device__ __forceinline__ void gather_row_u4(
    const unsigned int* __restrict__ meta, const uint4* __restrict__ curU4,
    int beg, int end, int sub, float* __restrict__ s) {
    float a0[8], a1[8];
    #pragma unroll
    for (int j = 0; j < 8; ++j) { a0[j] = 0.f; a1[j] = 0.f; }
    int i = beg;
    for (; i + 4 <= end; i += 4) {
        unsigned int m0 = __builtin_nontemporal_load(&meta[i]);
        unsigned int m1 = __builtin_nontemporal_load(&meta[i + 1]);
        unsigned int m2 = __builtin_nontemporal_load(&meta[i + 2]);
        unsigned int m3 = __builtin_nontemporal_load(&meta[i + 3]);
        uint4 p0 = curU4[((m0 & 0x1FFFF) << 4) + sub];
        uint4 p1 = curU4[((m1 & 0x1FFFF) << 4) + sub];
        uint4 p2 = curU4[((m2 & 0x1FFFF) << 4) + sub];
        uint4 p3 = curU4[((m3 & 0x1FFFF) << 4) + sub];
        float v0 = __uint_as_float((m0 >> 17) << 16);
        float v1 = __uint_as_float((m1 >> 17) << 16);
        float v2 = __uint_as_float((m2 >> 17) << 16);
        float v3 = __uint_as_float((m3 >> 17) << 16);
        a0[0] += bflo(p0.x) * v0; a0[1] += bfhi(p0.x) * v0;
        a0[2] += bflo(p0.y) * v0; a0[3] += bfhi(p0.y) * v0;
        a0[4] += bflo(p0.z) * v0; a0[5] += bfhi(p0.z) * v0;
        a0[6] += bflo(p0.w) * v0; a0[7] += bfhi(p0.w) * v0;
        a1[0] += bflo(p1.x) * v1; a1[1] += bfhi(p1.x) * v1;
        a1[2] += bflo(p1.y) * v1; a1[3] += bfhi(p1.y) * v1;
        a1[4] += bflo(p1.z) * v1; a1[5] += bfhi(p1.z) * v1;
        a1[6] += bflo(p1.w) * v1; a1[7] += bfhi(p1.w) * v1;
        a0[0] += bflo(p2.x) * v2; a0[1] += bfhi(p2.x) * v2;
        a0[2] += bflo(p2.y) * v2; a0[3] += bfhi(p2.y) * v2;
        a0[4] += bflo(p2.z) * v2; a0[5] += bfhi(p2.z) * v2;
        a0[6] += bflo(p2.w) * v2; a0[7] += bfhi(p2.w) * v2;
        a1[0] += bflo(p3.x) * v3; a1[1] += bfhi(p3.x) * v3;
        a1[2] += bflo(p3.y) * v3; a1[3] += bfhi(p3.y) * v3;
        a1[4] += bflo(p3.z) * v3; a1[5] += bfhi(p3.z) * v3;
        a1[6] += bflo(p3.w) * v3; a1[7] += bfhi(p3.w) * v3;
    }
    for (; i < end; ++i) {
        unsigned int m = __builtin_nontemporal_load(&meta[i]);
        uint4 p = curU4[((m & 0x1FFFF) << 4) + sub];
        float v = __uint_as_float((m >> 17) << 16);
        a0[0] += bflo(p.x) * v; a0[1] += bfhi(p.x) * v;
        a0[2] += bflo(p.y) * v; a0[3] += bfhi(p.y) * v;
        a0[4] += bflo(p.z) * v; a0[5] += bfhi(p.z) * v;
        a0[6] += bflo(p.w) * v; a0[7] += bfhi(p.w) * v;
    }
    #pragma unroll
    for (int j = 0; j < 8; ++j) s[j] = a0[j] + a1[j];
}

// ---------- gather (layers 1,2): 4 rows/wave, 16 rows/block ----------
__global__ void __launch_bounds__(256) gather_k(
    const int* __restrict__ rs, const unsigned int* __restrict__ meta,
    const uint4* __restrict__ cur, uint4* __restrict__ nxt) {
    int lane = threadIdx.x & 63;
    int row = blockIdx.x * 16 + (threadIdx.x >> 6) * 4 + (lane >> 4);
    if (row >= NNODES) return;
    int sub = lane & 15;
    float s[8];
    gather_row_u4(meta, cur, rs[row], rs[row + 1], sub, s);
    nxt[(row << 4) + sub] = make_uint4(pack2(s[0], s[1]), pack2(s[2], s[3]),
                                       pack2(s[4], s[5]), pack2(s[6], s[7]));
}

// ---------- layer 3 fused with final: out = E0 + L1 + L2 + sum ----------
__global__ void __launch_bounds__(256) gather_last_k(
    const int* __restrict__ rs, const unsigned int* __restrict__ meta,
    const uint4* __restrict__ cur,   // = L2 buffer
    const uint4* __restrict__ L1,
    const uint4* __restrict__ E0,
    float* __restrict__ out) {
    int lane = threadIdx.x & 63;
    int row = blockIdx.x * 16 + (threadIdx.x >> 6) * 4 + (lane >> 4);
    if (row >= NNODES) return;
    int sub = lane & 15;
    float s[8];
    gather_row_u4(meta, cur, rs[row], rs[row + 1], sub, s);
    uint4 e0 = E0[(row << 4) + sub];
    uint4 l1 = L1[(row << 4) + sub];
    uint4 l2 = cur[(row << 4) + sub];
    float4 o0, o1;
    o0.x = bflo(e0.x) + bflo(l1.x) + bflo(l2.x) + s[0];
    o0.y = bfhi(e0.x) + bfhi(l1.x) + bfhi(l2.x) + s[1];
    o0.z = bflo(e0.y) + bflo(l1.y) + bflo(l2.y) + s[2];
    o0.w = bfhi(e0.y) + bfhi(l1.y) + bfhi(l2.y) + s[3];
    o1.x = bflo(e0.z) + bflo(l1.z) + bflo(l2.z) + s[4];
    o1.y = bfhi(e0.z) + bfhi(l1.z) + bfhi(l2.z) + s[5];
    o1.z = bflo(e0.w) + bflo(l1.w) + bflo(l2.w) + s[6];
    o1.w = bfhi(e0.w) + bfhi(l1.w) + bfhi(l2.w) + s[7];
    float* op = out + (long)row * DIM + sub * 8;
    *(float4*)(op)     = o0;
    *(float4*)(op + 4) = o1;
}

// ---------- fallback: R2 atomic path ----------
__global__ void init_f32_k(const float* __restrict__ uE, const float* __restrict__ iE,
                           float* __restrict__ acc, float* __restrict__ cur) {
    long base = ((long)blockIdx.x * blockDim.x + threadIdx.x) * 8;
    if (base >= NELEM) return;
    const long usplit = (long)USERS * DIM;
    const float* s = (base < usplit) ? (uE + base) : (iE + (base - usplit));
    float4 f0 = *(const float4*)(s);
    float4 f1 = *(const float4*)(s + 4);
    *(float4*)(acc + base)     = f0;
    *(float4*)(acc + base + 4) = f1;
    *(float4*)(cur + base)     = f0;
    *(float4*)(cur + base + 4) = f1;
}
__global__ void scatter_k(const int* __restrict__ esrc, const int* __restrict__ edst,
                          const float* __restrict__ eval,
                          const float* __restrict__ cur, float* __restrict__ nxt) {
    long g = (long)blockIdx.x * blockDim.x + threadIdx.x;
    if (g >= (long)NEDGES * 32) return;
    int e  = (int)(g >> 5);
    int d0 = ((int)g & 31) * 4;
    float v = eval[e];
    float4 x = *(const float4*)(cur + (long)esrc[e] * DIM + d0);
    float* o = nxt + (long)edst[e] * DIM + d0;
    unsafeAtomicAdd(o + 0, x.x * v);
    unsafeAtomicAdd(o + 1, x.y * v);
    unsafeAtomicAdd(o + 2, x.z * v);
    unsafeAtomicAdd(o + 3, x.w * v);
}
__global__ void add_k(float* __restrict__ acc, const float* __restrict__ nxt) {
    long g = ((long)blockIdx.x * blockDim.x + threadIdx.x) * 4;
    if (g >= NELEM) return;
    float4 a = *(const float4*)(acc + g);
    float4 n = *(const float4*)(nxt + g);
    a.x += n.x; a.y += n.y; a.z += n.z; a.w += n.w;
    *(float4*)(acc + g) = a;
}

extern "C" void kernel_launch(void* const* d_in, const int* in_sizes, int n_in,
                              void* d_out, int out_size, void* d_ws, size_t ws_size,
                              hipStream_t stream) {
    const float* uE   = (const float*)d_in[0];
    const float* iE   = (const float*)d_in[1];
    const int*   esrc = (const int*)d_in[2];
    const int*   edst = (const int*)d_in[3];
    const float* eval = (const float*)d_in[4];
    float* out = (float*)d_out;

    char* ws = (char*)d_ws;
    const long NU = NELEM / 2;                      // uints per layer buffer
    unsigned int* E0  = (unsigned int*)ws;          // 25.6 MB
    unsigned int* L1  = E0 + NU;                    // 25.6 MB
    unsigned int* L2b = L1 + NU;                    // 25.6 MB
    unsigned int* meta = (unsigned int*)(L2b + NU); // 6.4 MB (packed)
    int*  rs     = (int*)(meta + NEDGES);           // NNODES+1
    int*  gcnt   = rs + NNODES + 1;                 // NBK
    int*  ssP    = gcnt + NBK;                      // NWG*SSROW (0.61 MB)
    size_t need  = (size_t)((char*)(ssP + NWG * SSROW) - ws);
    int2* tmp = (int2*)L2b;

    if (ws_size >= need) {
        hipMemsetAsync(gcnt, 0, (size_t)NBK * sizeof(int), stream);
        initpart_k<<<NWG + INITB, 256, 0, stream>>>(uE, iE, esrc, edst, eval,
                                                    E0, ssP, gcnt, tmp);
        fill2_k<<<NBK, 256, 0, stream>>>(tmp, ssP, gcnt, rs, meta);

        const int gblocks = (NNODES + 15) / 16;
        gather_k<<<gblocks, 256, 0, stream>>>(rs, meta, (const uint4*)E0, (uint4*)L1);
        gather_k<<<gblocks, 256, 0, stream>>>(rs, meta, (const uint4*)L1, (uint4*)L2b);
        gather_last_k<<<gblocks, 256, 0, stream>>>(rs, meta, (const uint4*)L2b,
                                                   (const uint4*)L1, (const uint4*)E0, out);
    } else {
        float* bufA = (float*)ws;
        float* bufB = bufA + NELEM;
        const size_t SZ = (size_t)NELEM * sizeof(float);
        init_f32_k<<<(int)((NELEM / 8 + 255) / 256), 256, 0, stream>>>(uE, iE, out, bufA);
        float* cur = bufA;
        float* nxt = bufB;
        for (int l = 0; l < 3; ++l) {
            hipMemsetAsync(nxt, 0, SZ, stream);
            long nthreads = (long)NEDGES * 32;
            scatter_k<<<(int)((nthreads + 255) / 256), 256, 0, stream>>>(esrc, edst, eval, cur, nxt);
            add_k<<<(int)((NELEM / 4 + 255) / 256), 256, 0, stream>>>(out, nxt);
            float* t = cur; cur = nxt; nxt = t;
        }
    }
}